// Round 10
// baseline (803.196 us; speedup 1.0000x reference)
//
#include <hip/hip_runtime.h>
#include <hip/hip_bf16.h>
#include <math.h>

typedef __attribute__((ext_vector_type(8))) __bf16 bf16x8;
typedef __attribute__((ext_vector_type(4))) float f32x4;
typedef __attribute__((ext_vector_type(4))) unsigned short u16x4;

#define HD  128   // hidden dim
#define LDP 136   // padded LDS row length (bf16 elems)

__device__ __forceinline__ unsigned short f2bf(float f) {
  __bf16 h = (__bf16)f;
  union { __bf16 h; unsigned short u; } v; v.h = h; return v.u;
}
__device__ __forceinline__ float bf2f(unsigned short h) {
  union { unsigned u; float f; } v; v.u = ((unsigned)h) << 16; return v.f;
}

__device__ __forceinline__ int idx_at(const void* p, long long i, int is64) {
  if (is64) return (int)((const long long*)p)[i];
  return ((const int*)p)[i];
}

// 128x128 += A(LDS bf16 LDP) @ B^T(LDS bf16 LDP). wave w: rows [w*32,w*32+32)
// D: m = w*32+mt*16+(lane>>4)*4+r, n = nt*16+(lane&15)
__device__ __forceinline__ void mfma_tile_128(const unsigned short* a_s,
                                              const unsigned short* w_s,
                                              int w, int l15, int lg,
                                              f32x4 acc[2][8]) {
#pragma unroll
  for (int kk = 0; kk < 4; ++kk) {
    bf16x8 a[2], b[8];
#pragma unroll
    for (int mt = 0; mt < 2; ++mt)
      a[mt] = *(const bf16x8*)&a_s[(w * 32 + mt * 16 + l15) * LDP + kk * 32 + lg * 8];
#pragma unroll
    for (int nt = 0; nt < 8; ++nt)
      b[nt] = *(const bf16x8*)&w_s[(nt * 16 + l15) * LDP + kk * 32 + lg * 8];
#pragma unroll
    for (int mt = 0; mt < 2; ++mt)
#pragma unroll
      for (int nt = 0; nt < 8; ++nt)
        acc[mt][nt] = __builtin_amdgcn_mfma_f32_16x16x32_bf16(a[mt], b[nt], acc[mt][nt], 0, 0, 0);
  }
}

// same but B fragments straight from GLOBAL bf16 [128][128] (L2-hot weights)
__device__ __forceinline__ void mfma_tile_gb(const unsigned short* a_s,
                                             const unsigned short* Wb,
                                             int w, int l15, int lg,
                                             f32x4 acc[2][8]) {
#pragma unroll
  for (int kk = 0; kk < 4; ++kk) {
    bf16x8 a[2], b[8];
#pragma unroll
    for (int mt = 0; mt < 2; ++mt)
      a[mt] = *(const bf16x8*)&a_s[(w * 32 + mt * 16 + l15) * LDP + kk * 32 + lg * 8];
#pragma unroll
    for (int nt = 0; nt < 8; ++nt)
      b[nt] = *(const bf16x8*)&Wb[(nt * 16 + l15) * 128 + kk * 32 + lg * 8];
#pragma unroll
    for (int mt = 0; mt < 2; ++mt)
#pragma unroll
      for (int nt = 0; nt < 8; ++nt)
        acc[mt][nt] = __builtin_amdgcn_mfma_f32_16x16x32_bf16(a[mt], b[nt], acc[mt][nt], 0, 0, 0);
  }
}

__device__ __forceinline__ void stage_f32s(unsigned short* dst, const float* src,
                                           long long src_ld, int tid, int T) {
  for (int i = tid; i < 128 * 32; i += T) {
    int r = i >> 5, c = (i & 31) << 2;
    float4 f = *(const float4*)&src[(long long)r * src_ld + c];
    u16x4 h = { f2bf(f.x), f2bf(f.y), f2bf(f.z), f2bf(f.w) };
    *(u16x4*)&dst[r * LDP + c] = h;
  }
}

// ---------------- index dtype detector ----------------
__global__ void detect_idx_kernel(const void* __restrict__ ei, int E, int N,
                                  int* __restrict__ flag) {
  if (threadIdx.x == 0 && blockIdx.x == 0) {
    const long long* p = (const long long*)ei;
    int is64 = 1;
    long long step = E / 64; if (step < 1) step = 1;
    for (int i = 0; i < 64; ++i) {
      long long v = p[i * step];
      if (v < 0 || v >= N) { is64 = 0; break; }
    }
    *flag = is64;
  }
}

// ---------------- f32 -> bf16 pre-converts ----------------
__global__ __launch_bounds__(256) void conv_we_kernel(const float* __restrict__ We,
                                                      unsigned short* __restrict__ we_bf) {
  int i = blockIdx.x * 256 + threadIdx.x;
  if (i < 128 * 128) {
    int r = i >> 7, c = i & 127;
    we_bf[r * 136 + c] = f2bf(We[i]);
  }
}
__global__ __launch_bounds__(256) void conv_w_kernel(const float* __restrict__ W,
                                                     unsigned short* __restrict__ out,
                                                     int n) {
  int i = blockIdx.x * 256 + threadIdx.x;
  if (i < n) out[i] = f2bf(W[i]);
}
__global__ __launch_bounds__(256) void conv_x_kernel(const float* __restrict__ x,
                                                     unsigned short* __restrict__ xb,
                                                     long long n8) {
  long long i = blockIdx.x * 256LL + threadIdx.x;
  if (i < n8) {
    float4 f0 = *(const float4*)&x[i * 8];
    float4 f1 = *(const float4*)&x[i * 8 + 4];
    u16x4 h0 = { f2bf(f0.x), f2bf(f0.y), f2bf(f0.z), f2bf(f0.w) };
    u16x4 h1 = { f2bf(f1.x), f2bf(f1.y), f2bf(f1.z), f2bf(f1.w) };
    *(u16x4*)&xb[i * 8] = h0;
    *(u16x4*)&xb[i * 8 + 4] = h1;
  }
}

// ---------------- dst histogram ----------------
__global__ __launch_bounds__(256) void hist_kernel(const void* __restrict__ ei,
                                                   const int* __restrict__ flag,
                                                   int* __restrict__ deg, int E) {
  const int is64 = *flag;
  for (long long e = blockIdx.x * 256LL + threadIdx.x; e < E;
       e += (long long)gridDim.x * 256)
    atomicAdd(&deg[idx_at(ei, (long long)E + e, is64)], 1);
}

// ---------------- 3-phase exclusive scan ----------------
#define SCH 1024
__global__ __launch_bounds__(256) void scan_a(const int* __restrict__ deg,
                                              int* __restrict__ bsum, int N) {
  const int b = blockIdx.x, t = threadIdx.x;
  int p = 0;
#pragma unroll
  for (int k = 0; k < 4; ++k) {
    int idx = b * SCH + t * 4 + k;
    if (idx < N) p += deg[idx];
  }
  __shared__ int warr[4];
  for (int o = 32; o > 0; o >>= 1) p += __shfl_xor(p, o);
  if ((t & 63) == 0) warr[t >> 6] = p;
  __syncthreads();
  if (t == 0) bsum[b] = warr[0] + warr[1] + warr[2] + warr[3];
}
__global__ void scan_b(int* __restrict__ bsum, int* __restrict__ off, int NB, int N) {
  if (threadIdx.x == 0 && blockIdx.x == 0) {
    int run = 0;
    for (int b = 0; b < NB; ++b) { int t = bsum[b]; bsum[b] = run; run += t; }
    off[N] = run;
  }
}
__global__ __launch_bounds__(128) void scan_b2(int* __restrict__ bsum,
                                               int* __restrict__ off, int NB, int N) {
  __shared__ int arr[128];
  const int t = threadIdx.x;
  int v = (t < NB) ? bsum[t] : 0;
  arr[t] = v;
  __syncthreads();
  for (int s = 1; s < 128; s <<= 1) {
    int u = (t >= s) ? arr[t - s] : 0;
    __syncthreads();
    arr[t] += u;
    __syncthreads();
  }
  if (t < NB) bsum[t] = arr[t] - v;   // exclusive
  if (t == 0) off[N] = arr[127];      // total
}
__global__ __launch_bounds__(256) void scan_c(const int* __restrict__ deg,
                                              const int* __restrict__ bsum,
                                              int* __restrict__ off,
                                              int* __restrict__ cursor, int N) {
  const int b = blockIdx.x, t = threadIdx.x;
  int d[4], s = 0;
#pragma unroll
  for (int k = 0; k < 4; ++k) {
    int idx = b * SCH + t * 4 + k;
    d[k] = (idx < N) ? deg[idx] : 0;
    s += d[k];
  }
  __shared__ int arr[256];
  arr[t] = s;
  __syncthreads();
  for (int stp = 1; stp < 256; stp <<= 1) {
    int v = (t >= stp) ? arr[t - stp] : 0;
    __syncthreads();
    arr[t] += v;
    __syncthreads();
  }
  int base = bsum[b] + arr[t] - s;
  int acc = 0;
#pragma unroll
  for (int k = 0; k < 4; ++k) {
    int idx = b * SCH + t * 4 + k;
    if (idx < N) { off[idx] = base + acc; cursor[idx] = base + acc; }
    acc += d[k];
  }
}

// ---------------- scatter edge ids into dst-sorted CSR order ----------------
__global__ __launch_bounds__(256) void scatter_eid_kernel(
    const void* __restrict__ ei, const int* __restrict__ flag,
    int* __restrict__ cursor, int* __restrict__ eid, int E) {
  const int is64 = *flag;
  for (long long e = blockIdx.x * 256LL + threadIdx.x; e < E;
       e += (long long)gridDim.x * 256) {
    int d = idx_at(ei, (long long)E + e, is64);
    int pos = atomicAdd(&cursor[d], 1);
    eid[pos] = (int)e;
  }
}

// -------- edge kernel v10: FULLY STREAMING — msg[e] in edge order, no atomics ------
__global__ __launch_bounds__(256, 4) void edge_kernel10(
    const unsigned short* __restrict__ x_bf, const float* __restrict__ ea,
    const unsigned short* __restrict__ we_bf, const float* __restrict__ be,
    const void* __restrict__ ei, const int* __restrict__ flag,
    unsigned short* __restrict__ msg, int E) {
  __shared__ unsigned short we_s[128 * LDP];   // 34816 B; reused as gemm-out staging
  __shared__ int s_src[128];
  const int tid = threadIdx.x;
  const long long e0 = (long long)blockIdx.x * 128;
  const int is64 = *flag;

  if (tid < 128) {
    long long e = e0 + tid;
    s_src[tid] = (e < E) ? idx_at(ei, e, is64) : 0;
  }

  const int lane = tid & 63, w = tid >> 6;
  const int l15 = lane & 15, lg = lane >> 4;

  // A fragments from global (streaming, edge order)
  float4 af[2][4][2];
#pragma unroll
  for (int mt = 0; mt < 2; ++mt) {
    long long row = e0 + w * 32 + mt * 16 + l15;
    const float* src = &ea[(row < E ? row : e0) * HD + lg * 8];
#pragma unroll
    for (int kk = 0; kk < 4; ++kk) {
      af[mt][kk][0] = *(const float4*)&src[kk * 32];
      af[mt][kk][1] = *(const float4*)&src[kk * 32 + 4];
    }
  }

  // stage pre-converted bf16 We (pure 16B copies)
  for (int i = tid; i < 2048; i += 256) {
    int r = i >> 4, c = (i & 15) << 3;
    *(float4*)&we_s[r * LDP + c] = *(const float4*)&we_bf[r * 136 + c];
  }

  bf16x8 a[2][4];
#pragma unroll
  for (int mt = 0; mt < 2; ++mt)
#pragma unroll
    for (int kk = 0; kk < 4; ++kk) {
      float4 f0 = af[mt][kk][0], f1 = af[mt][kk][1];
      bf16x8 t;
      t[0] = (__bf16)f0.x; t[1] = (__bf16)f0.y; t[2] = (__bf16)f0.z; t[3] = (__bf16)f0.w;
      t[4] = (__bf16)f1.x; t[5] = (__bf16)f1.y; t[6] = (__bf16)f1.z; t[7] = (__bf16)f1.w;
      a[mt][kk] = t;
    }
  __syncthreads();

  f32x4 acc[2][8];
#pragma unroll
  for (int mt = 0; mt < 2; ++mt)
#pragma unroll
    for (int nt = 0; nt < 8; ++nt) acc[mt][nt] = (f32x4){0.f, 0.f, 0.f, 0.f};

#pragma unroll
  for (int kk = 0; kk < 4; ++kk) {
    bf16x8 b[8];
#pragma unroll
    for (int nt = 0; nt < 8; ++nt)
      b[nt] = *(const bf16x8*)&we_s[(nt * 16 + l15) * LDP + kk * 32 + lg * 8];
#pragma unroll
    for (int mt = 0; mt < 2; ++mt)
#pragma unroll
      for (int nt = 0; nt < 8; ++nt)
        acc[mt][nt] = __builtin_amdgcn_mfma_f32_16x16x32_bf16(a[mt][kk], b[nt], acc[mt][nt], 0, 0, 0);
  }

  float bev[8];
#pragma unroll
  for (int nt = 0; nt < 8; ++nt) bev[nt] = be[nt * 16 + l15];
  __syncthreads();  // all We reads done -> reuse we_s as gemm-out staging

  // epilogue 1: store (gemm + be) to LDS bf16
#pragma unroll
  for (int mt = 0; mt < 2; ++mt)
#pragma unroll
    for (int r = 0; r < 4; ++r) {
      int m = w * 32 + mt * 16 + lg * 4 + r;
#pragma unroll
      for (int nt = 0; nt < 8; ++nt)
        we_s[m * LDP + nt * 16 + l15] = f2bf(acc[mt][nt][r] + bev[nt]);
    }
  __syncthreads();

  // epilogue 2: bf16 x-row read (L3-served) + relu + STREAMING msg write (edge order)
  unsigned short* mbase = msg + (size_t)e0 * 128;
  const int rows = (E - e0 < 128) ? (int)(E - e0) : 128;
  for (int i = tid; i < rows * 16; i += 256) {
    int r = i >> 4, sg = i & 15;
    bf16x8 xv = *(const bf16x8*)&x_bf[(size_t)s_src[r] * HD + sg * 8];
    bf16x8 g = *(const bf16x8*)&we_s[r * LDP + sg * 8];
    u16x4 h0, h1;
#pragma unroll
    for (int k = 0; k < 4; ++k) {
      float v = (float)g[k] + (float)xv[k];
      h0[k] = f2bf(v > 0.f ? v : 0.f);
    }
#pragma unroll
    for (int k = 0; k < 4; ++k) {
      float v = (float)g[4 + k] + (float)xv[4 + k];
      h1[k] = f2bf(v > 0.f ? v : 0.f);
    }
    unsigned short* mp = &mbase[(size_t)r * 128 + sg * 8];
    *(u16x4*)&mp[0] = h0;
    *(u16x4*)&mp[4] = h1;
  }
}

// -------- gather kernel v10: h = x + segsum(msg[eid[j]]), permuted READS ----------
__global__ __launch_bounds__(256) void gather_kernel10(
    const unsigned short* __restrict__ x_bf, const int* __restrict__ off,
    const int* __restrict__ eid, const unsigned short* __restrict__ msg,
    unsigned short* __restrict__ h_bf, int N) {
  const int tid = threadIdx.x;
  const int grp = tid >> 4, li = tid & 15;   // 16 rows/block, 16 lanes/row
  const long long row = (long long)blockIdx.x * 16 + grp;
  if (row >= N) return;
  const int co = li * 8;
  float a8[8];
  bf16x8 xv = *(const bf16x8*)&x_bf[row * HD + co];
#pragma unroll
  for (int k = 0; k < 8; ++k) a8[k] = (float)xv[k];
  const int j0 = off[row], j1 = off[row + 1];
  int j = j0;
  for (; j + 3 < j1; j += 4) {
    int e0 = eid[j], e1 = eid[j + 1], e2 = eid[j + 2], e3 = eid[j + 3];
    bf16x8 v0 = *(const bf16x8*)&msg[(size_t)e0 * 128 + co];
    bf16x8 v1 = *(const bf16x8*)&msg[(size_t)e1 * 128 + co];
    bf16x8 v2 = *(const bf16x8*)&msg[(size_t)e2 * 128 + co];
    bf16x8 v3 = *(const bf16x8*)&msg[(size_t)e3 * 128 + co];
#pragma unroll
    for (int k = 0; k < 8; ++k)
      a8[k] += ((float)v0[k] + (float)v1[k]) + ((float)v2[k] + (float)v3[k]);
  }
  for (; j < j1; ++j) {
    bf16x8 v0 = *(const bf16x8*)&msg[(size_t)eid[j] * 128 + co];
#pragma unroll
    for (int k = 0; k < 8; ++k) a8[k] += (float)v0[k];
  }
  bf16x8 hv;
#pragma unroll
  for (int k = 0; k < 8; ++k) hv[k] = (__bf16)a8[k];
  *(bf16x8*)&h_bf[row * HD + co] = hv;
}

// -------- mlp kernel: xo = LN1(x + mlp(h)), h pre-gathered bf16 -------------------
__global__ __launch_bounds__(256, 4) void mlp_kernel(
    const float* __restrict__ x, float* __restrict__ xo,
    const unsigned short* __restrict__ h_bf,
    const unsigned short* __restrict__ W1b, const float* __restrict__ b1,
    const unsigned short* __restrict__ W2b, const float* __restrict__ b2,
    const float* __restrict__ g1, const float* __restrict__ bt1, int N) {
  __shared__ unsigned short a_s[128 * LDP];   // 34816 B only
  const int tid = threadIdx.x;
  const long long r0 = (long long)blockIdx.x * 128;

  for (int i = tid; i < 2048; i += 256) {
    int r = i >> 4, c = (i & 15) << 3;
    long long gr = r0 + r;
    bf16x8 v;
    if (gr < N) v = *(const bf16x8*)&h_bf[gr * HD + c];
    else {
#pragma unroll
      for (int k = 0; k < 8; ++k) v[k] = (__bf16)0.f;
    }
    *(bf16x8*)&a_s[r * LDP + c] = v;
  }
  __syncthreads();

  const int lane = tid & 63, w = tid >> 6;
  const int l15 = lane & 15, lg = lane >> 4;
  f32x4 acc[2][8];
#pragma unroll
  for (int mt = 0; mt < 2; ++mt)
#pragma unroll
    for (int nt = 0; nt < 8; ++nt) acc[mt][nt] = (f32x4){0.f, 0.f, 0.f, 0.f};
  mfma_tile_gb(a_s, W1b, w, l15, lg, acc);
  __syncthreads();

#pragma unroll
  for (int mt = 0; mt < 2; ++mt)
#pragma unroll
    for (int r = 0; r < 4; ++r) {
      int m = w * 32 + mt * 16 + lg * 4 + r;
#pragma unroll
      for (int nt = 0; nt < 8; ++nt) {
        int n = nt * 16 + l15;
        float t = acc[mt][nt][r] + b1[n];
        a_s[m * LDP + n] = f2bf(t > 0.f ? t : 0.f);
      }
    }
  __syncthreads();

  f32x4 acc2[2][8];
#pragma unroll
  for (int mt = 0; mt < 2; ++mt)
#pragma unroll
    for (int nt = 0; nt < 8; ++nt) acc2[mt][nt] = (f32x4){0.f, 0.f, 0.f, 0.f};
  mfma_tile_gb(a_s, W2b, w, l15, lg, acc2);
  __syncthreads();

#pragma unroll
  for (int mt = 0; mt < 2; ++mt)
#pragma unroll
    for (int r = 0; r < 4; ++r) {
      int m = w * 32 + mt * 16 + lg * 4 + r;
      if (r0 + m < N) {
#pragma unroll
        for (int nt = 0; nt < 8; ++nt) {
          int n = nt * 16 + l15;
          a_s[m * LDP + n] = f2bf(x[(r0 + m) * HD + n] + acc2[mt][nt][r] + b2[n]);
        }
      }
    }
  __syncthreads();

  for (int row = w; row < 128; row += 4) {
    if (r0 + row >= N) continue;
    float v1 = bf2f(a_s[row * LDP + lane]), v2 = bf2f(a_s[row * LDP + 64 + lane]);
    float s = v1 + v2, sq = v1 * v1 + v2 * v2;
    for (int o = 32; o > 0; o >>= 1) { s += __shfl_xor(s, o); sq += __shfl_xor(sq, o); }
    float mean = s * (1.f / 128.f);
    float var = sq * (1.f / 128.f) - mean * mean;
    float rs = rsqrtf(var + 1e-5f);
    xo[(r0 + row) * HD + lane]      = (v1 - mean) * rs * g1[lane] + bt1[lane];
    xo[(r0 + row) * HD + 64 + lane] = (v2 - mean) * rs * g1[lane + 64] + bt1[lane + 64];
  }
}

// ================= FALLBACK (small ws): atomic path =================
__global__ __launch_bounds__(256) void edge_kernel(
    const float* __restrict__ x, const float* __restrict__ ea,
    const float* __restrict__ We, const float* __restrict__ be,
    const void* __restrict__ ei, const int* __restrict__ flag,
    float* __restrict__ agg, int E, int N) {
  __shared__ unsigned short ea_s[128 * LDP];
  __shared__ unsigned short we_s[128 * LDP];
  __shared__ int s_src[128];
  __shared__ int s_dst[128];
  const int tid = threadIdx.x;
  const long long e0 = (long long)blockIdx.x * 128;
  const int is64 = *flag;
  if (tid < 128) {
    long long e = e0 + tid;
    int s = 0, d = 0;
    if (e < E) { s = idx_at(ei, e, is64); d = idx_at(ei, (long long)E + e, is64); }
    s_src[tid] = s; s_dst[tid] = d;
  }
  for (int i = tid; i < 128 * 32; i += 256) {
    int r = i >> 5, c = (i & 31) << 2;
    float4 f = {0.f, 0.f, 0.f, 0.f};
    if (e0 + r < E) f = *(const float4*)&ea[(e0 + r) * HD + c];
    u16x4 h = { f2bf(f.x), f2bf(f.y), f2bf(f.z), f2bf(f.w) };
    *(u16x4*)&ea_s[r * LDP + c] = h;
    float4 g = *(const float4*)&We[r * HD + c];
    u16x4 hw = { f2bf(g.x), f2bf(g.y), f2bf(g.z), f2bf(g.w) };
    *(u16x4*)&we_s[r * LDP + c] = hw;
  }
  __syncthreads();
  const int lane = tid & 63, w = tid >> 6;
  const int l15 = lane & 15, lg = lane >> 4;
  f32x4 acc[2][8];
#pragma unroll
  for (int mt = 0; mt < 2; ++mt)
#pragma unroll
    for (int nt = 0; nt < 8; ++nt) acc[mt][nt] = (f32x4){0.f, 0.f, 0.f, 0.f};
  mfma_tile_128(ea_s, we_s, w, l15, lg, acc);
  float bev[8];
#pragma unroll
  for (int nt = 0; nt < 8; ++nt) bev[nt] = be[nt * 16 + l15];
#pragma unroll
  for (int mt = 0; mt < 2; ++mt) {
#pragma unroll
    for (int r = 0; r < 4; ++r) {
      int m = w * 32 + mt * 16 + lg * 4 + r;
      if (e0 + m >= E) continue;
      const float* xrow = x + (size_t)s_src[m] * HD;
      float* arow = agg + (size_t)s_dst[m] * HD;
#pragma unroll
      for (int nt = 0; nt < 8; ++nt) {
        int n = nt * 16 + l15;
        float val = acc[mt][nt][r] + bev[nt] + xrow[n];
        if (val > 0.f) unsafeAtomicAdd(&arow[n], val);
      }
    }
  }
}

__global__ __launch_bounds__(256) void node_kernel(
    const float* __restrict__ x, float* xo,
    const float* __restrict__ W1, const float* __restrict__ b1,
    const float* __restrict__ W2, const float* __restrict__ b2,
    const float* __restrict__ g1, const float* __restrict__ bt1, int N) {
  __shared__ char smem[2 * 128 * LDP * 2];
  unsigned short* a_s = (unsigned short*)smem;
  unsigned short* w_s = (unsigned short*)smem + 128 * LDP;
  float* y_s = (float*)smem;
  const int tid = threadIdx.x;
  const long long r0 = (long long)blockIdx.x * 128;
  for (int i = tid; i < 128 * 32; i += 256) {
    int r = i >> 5, c = (i & 31) << 2;
    float4 f = {0.f, 0.f, 0.f, 0.f};
    if (r0 + r < N) {
      float4 xa = *(const float4*)&x[(r0 + r) * HD + c];
      float4 ag = *(const float4*)&xo[(r0 + r) * HD + c];
      f.x = xa.x + ag.x; f.y = xa.y + ag.y; f.z = xa.z + ag.z; f.w = xa.w + ag.w;
    }
    u16x4 h = { f2bf(f.x), f2bf(f.y), f2bf(f.z), f2bf(f.w) };
    *(u16x4*)&a_s[r * LDP + c] = h;
    float4 g = *(const float4*)&W1[r * HD + c];
    u16x4 hw = { f2bf(g.x), f2bf(g.y), f2bf(g.z), f2bf(g.w) };
    *(u16x4*)&w_s[r * LDP + c] = hw;
  }
  __syncthreads();
  const int lane = tid & 63, w = tid >> 6;
  const int l15 = lane & 15, lg = lane >> 4;
  f32x4 acc[2][8];
#pragma unroll
  for (int mt = 0; mt < 2; ++mt)
#pragma unroll
    for (int nt = 0; nt < 8; ++nt) acc[mt][nt] = (f32x4){0.f, 0.f, 0.f, 0.f};
  mfma_tile_128(a_s, w_s, w, l15, lg, acc);
  __syncthreads();
#pragma unroll
  for (int mt = 0; mt < 2; ++mt)
#pragma unroll
    for (int r = 0; r < 4; ++r) {
      int m = w * 32 + mt * 16 + lg * 4 + r;
#pragma unroll
      for (int nt = 0; nt < 8; ++nt) {
        int n = nt * 16 + l15;
        float t = acc[mt][nt][r] + b1[n];
        a_s[m * LDP + n] = f2bf(t > 0.f ? t : 0.f);
      }
    }
  stage_f32s(w_s, W2, HD, tid, 256);
  __syncthreads();
  f32x4 acc2[2][8];
#pragma unroll
  for (int mt = 0; mt < 2; ++mt)
#pragma unroll
    for (int nt = 0; nt < 8; ++nt) acc2[mt][nt] = (f32x4){0.f, 0.f, 0.f, 0.f};
  mfma_tile_128(a_s, w_s, w, l15, lg, acc2);
  __syncthreads();
#pragma unroll
  for (int mt = 0; mt < 2; ++mt)
#pragma unroll
    for (int r = 0; r < 4; ++r) {
      int m = w * 32 + mt * 16 + lg * 4 + r;
      if (r0 + m < N) {
#pragma unroll
        for (int nt = 0; nt < 8; ++nt) {
          int n = nt * 16 + l15;
          y_s[m * 132 + n] = x[(r0 + m) * HD + n] + acc2[mt][nt][r] + b2[n];
        }
      }
    }
  __syncthreads();
  for (int row = w; row < 128; row += 4) {
    if (r0 + row >= N) continue;
    float v1 = y_s[row * 132 + lane], v2 = y_s[row * 132 + 64 + lane];
    float s = v1 + v2, sq = v1 * v1 + v2 * v2;
    for (int o = 32; o > 0; o >>= 1) { s += __shfl_xor(s, o); sq += __shfl_xor(sq, o); }
    float mean = s * (1.f / 128.f);
    float var = sq * (1.f / 128.f) - mean * mean;
    float rs = rsqrtf(var + 1e-5f);
    xo[(r0 + row) * HD + lane]      = (v1 - mean) * rs * g1[lane] + bt1[lane];
    xo[(r0 + row) * HD + 64 + lane] = (v2 - mean) * rs * g1[lane + 64] + bt1[lane + 64];
  }
}

// ---------------- qkv = xc @ in_w^T + in_b ----------------
__global__ __launch_bounds__(256) void qkv_kernel(
    const float* __restrict__ xo, const float* __restrict__ in_w,
    const float* __restrict__ in_b, const void* __restrict__ chem,
    const int* __restrict__ flag, float* __restrict__ qkv) {
  __shared__ unsigned short a_s[128 * LDP];
  __shared__ unsigned short w_s[128 * LDP];
  __shared__ int s_row[128];
  const int tid = threadIdx.x;
  const int chunk = blockIdx.x, sec = blockIdx.y;
  const int is64 = *flag;
  if (tid < 128) s_row[tid] = idx_at(chem, (long long)chunk * 128 + tid, is64);
  __syncthreads();
  for (int i = tid; i < 128 * 32; i += 256) {
    int r = i >> 5, c = (i & 31) << 2;
    float4 f = *(const float4*)&xo[(size_t)s_row[r] * HD + c];
    u16x4 h = { f2bf(f.x), f2bf(f.y), f2bf(f.z), f2bf(f.w) };
    *(u16x4*)&a_s[r * LDP + c] = h;
    float4 g = *(const float4*)&in_w[(size_t)(sec * 128 + r) * HD + c];
    u16x4 hw = { f2bf(g.x), f2bf(g.y), f2bf(g.z), f2bf(g.w) };
    *(u16x4*)&w_s[r * LDP + c] = hw;
  }
  __syncthreads();
  const int lane = tid & 63, w = tid >> 6;
  const int l15 = lane & 15, lg = lane >> 4;
  f32x4 acc[2][8];
#pragma unroll
  for (int mt = 0; mt < 2; ++mt)
#pragma unroll
    for (int nt = 0; nt < 8; ++nt) acc[mt][nt] = (f32x4){0.f, 0.f, 0.f, 0.f};
  mfma_tile_128(a_s, w_s, w, l15, lg, acc);
#pragma unroll
  for (int mt = 0; mt < 2; ++mt)
#pragma unroll
    for (int r = 0; r < 4; ++r) {
      int m = w * 32 + mt * 16 + lg * 4 + r;
#pragma unroll
      for (int nt = 0; nt < 8; ++nt) {
        int n = nt * 16 + l15;
        qkv[(size_t)(chunk * 128 + m) * 384 + sec * 128 + n] = acc[mt][nt][r] + in_b[sec * 128 + n];
      }
    }
}

// ---------------- attention per (chunk, head) ----------------
__global__ __launch_bounds__(128) void attn_kernel(const float* __restrict__ qkv,
                                                   float* __restrict__ o) {
  __shared__ float k_s[128 * 32];
  __shared__ float v_s[128 * 32];
  const int tid = threadIdx.x;
  const int chunk = blockIdx.x, h = blockIdx.y;
  const float scale = 0.1767766952966369f;  // 1/sqrt(32)
  for (int i = tid; i < 128 * 32; i += 128) {
    int r = i >> 5, d = i & 31;
    k_s[i] = qkv[(size_t)(chunk * 128 + r) * 384 + 128 + h * 32 + d];
    v_s[i] = qkv[(size_t)(chunk * 128 + r) * 384 + 256 + h * 32 + d];
  }
  float qr[32];
  const int m = tid;
#pragma unroll
  for (int d = 0; d < 32; ++d)
    qr[d] = qkv[(size_t)(chunk * 128 + m) * 384 + h * 32 + d] * scale;
  __syncthreads();
  float mx = -1e30f, sm = 0.f;
  for (int j = 0; j < 128; ++j) {
    float s = 0.f;
#pragma unroll
    for (int d = 0; d < 32; ++d) s += qr[d] * k_s[j * 32 + d];
    if (s > mx) { sm = sm * __expf(mx - s); mx = s; }
    sm += __expf(s - mx);
  }
  const float inv = 1.f / sm;
  float ov[32];
#pragma unroll
  for (int d = 0; d < 32; ++d) ov[d] = 0.f;
  for (int j = 0; j < 128; ++j) {
    float s = 0.f;
#pragma unroll
    for (int d = 0; d < 32; ++d) s += qr[d] * k_s[j * 32 + d];
    float p = __expf(s - mx) * inv;
#pragma unroll
    for (int d = 0; d < 32; ++d) ov[d] += p * v_s[j * 32 + d];
  }
#pragma unroll
  for (int d = 0; d < 32; ++d)
    o[(size_t)(chunk * 128 + m) * HD + h * 32 + d] = ov[d];
}

// -------- out-proj + residual + LN2 --------
__global__ __launch_bounds__(256) void oproj_kernel(
    const float* __restrict__ xo, const float* __restrict__ o,
    const float* __restrict__ Wo, const float* __restrict__ bo,
    const float* __restrict__ g2, const float* __restrict__ bt2,
    const void* __restrict__ chem, const int* __restrict__ flag,
    float* __restrict__ xc2, unsigned short* __restrict__ h2b) {
  __shared__ char smem[2 * 128 * LDP * 2];
  unsigned short* a_s = (unsigned short*)smem;
  unsigned short* w_s = (unsigned short*)smem + 128 * LDP;
  float* y_s = (float*)smem;
  __shared__ int s_row[128];
  const int tid = threadIdx.x;
  const int chunk = blockIdx.x;
  const int is64 = *flag;
  if (tid < 128) s_row[tid] = idx_at(chem, (long long)chunk * 128 + tid, is64);
  stage_f32s(a_s, o + (size_t)chunk * 128 * HD, HD, tid, 256);
  stage_f32s(w_s, Wo, HD, tid, 256);
  __syncthreads();
  const int lane = tid & 63, w = tid >> 6;
  const int l15 = lane & 15, lg = lane >> 4;
  f32x4 acc[2][8];
#pragma unroll
  for (int mt = 0; mt < 2; ++mt)
#pragma unroll
    for (int nt = 0; nt < 8; ++nt) acc[mt][nt] = (f32x4){0.f, 0.f, 0.f, 0.f};
  mfma_tile_128(a_s, w_s, w, l15, lg, acc);
  __syncthreads();
#pragma unroll
  for (int mt = 0; mt < 2; ++mt)
#pragma unroll
    for (int r = 0; r < 4; ++r) {
      int m = w * 32 + mt * 16 + lg * 4 + r;
#pragma unroll
      for (int nt = 0; nt < 8; ++nt) {
        int n = nt * 16 + l15;
        y_s[m * 132 + n] = xo[(size_t)s_row[m] * HD + n] + acc[mt][nt][r] + bo[n];
      }
    }
  __syncthreads();
  for (int row = w; row < 128; row += 4) {
    float v1 = y_s[row * 132 + lane], v2 = y_s[row * 132 + 64 + lane];
    float s = v1 + v2, sq = v1 * v1 + v2 * v2;
    for (int o2 = 32; o2 > 0; o2 >>= 1) { s += __shfl_xor(s, o2); sq += __shfl_xor(sq, o2); }
    float mean = s * (1.f / 128.f);
    float var = sq * (1.f / 128.f) - mean * mean;
    float rs = rsqrtf(var + 1e-5f);
    size_t gi = (size_t)(chunk * 128 + row) * HD;
    xc2[gi + lane] = v1; xc2[gi + 64 + lane] = v2;
    h2b[gi + lane]      = f2bf((v1 - mean) * rs * g2[lane] + bt2[lane]);
    h2b[gi + 64 + lane] = f2bf((v2 - mean) * rs * g2[lane + 64] + bt2[lane + 64]);
  }
}

// ---------------- ffn1 ----------------
__global__ __launch_bounds__(256) void ffn1_kernel(
    const unsigned short* __restrict__ h2b, const float* __restrict__ f1w,
    const float* __restrict__ f1b, unsigned short* __restrict__ u) {
  __shared__ unsigned short a_s[128 * LDP];
  __shared__ unsigned short w_s[128 * LDP];
  const int tid = threadIdx.x;
  const int chunk = blockIdx.x, sec = blockIdx.y;
  for (int i = tid; i < 128 * 32; i += 256) {
    int r = i >> 5, c = (i & 31) << 2;
    *(u16x4*)&a_s[r * LDP + c] = *(const u16x4*)&h2b[(size_t)(chunk * 128 + r) * HD + c];
  }
  stage_f32s(w_s, f1w + (size_t)sec * 128 * HD, HD, tid, 256);
  __syncthreads();
  const int lane = tid & 63, w = tid >> 6;
  const int l15 = lane & 15, lg = lane >> 4;
  f32x4 acc[2][8];
#pragma unroll
  for (int mt = 0; mt < 2; ++mt)
#pragma unroll
    for (int nt = 0; nt < 8; ++nt) acc[mt][nt] = (f32x4){0.f, 0.f, 0.f, 0.f};
  mfma_tile_128(a_s, w_s, w, l15, lg, acc);
#pragma unroll
  for (int mt = 0; mt < 2; ++mt)
#pragma unroll
    for (int r = 0; r < 4; ++r) {
      int m = w * 32 + mt * 16 + lg * 4 + r;
#pragma unroll
      for (int nt = 0; nt < 8; ++nt) {
        int n = nt * 16 + l15;
        float t = acc[mt][nt][r] + f1b[sec * 128 + n];
        u[(size_t)(chunk * 128 + m) * 256 + sec * 128 + n] = f2bf(t > 0.f ? t : 0.f);
      }
    }
}

// ---------------- ffn2 ----------------
__global__ __launch_bounds__(256) void ffn2_kernel(
    const unsigned short* __restrict__ u, const float* __restrict__ f2w,
    const float* __restrict__ f2b, const float* __restrict__ xc2,
    const void* __restrict__ chem, const int* __restrict__ flag,
    float* __restrict__ out) {
  __shared__ unsigned short a_s[128 * LDP];
  __shared__ unsigned short w_s[128 * LDP];
  __shared__ int s_row[128];
  const int tid = threadIdx.x;
  const int chunk = blockIdx.x;
  const int is64 = *flag;
  if (tid < 128) s_row[tid] = idx_at(chem, (long long)chunk * 128 + tid, is64);
  const int lane = tid & 63, w = tid >> 6;
  const int l15 = lane & 15, lg = lane >> 4;
  f32x4 acc[2][8];
#pragma unroll
  for (int mt = 0; mt < 2; ++mt)
#pragma unroll
    for (int nt = 0; nt < 8; ++nt) acc[mt][nt] = (f32x4){0.f, 0.f, 0.f, 0.f};
  for (int half = 0; half < 2; ++half) {
    __syncthreads();
    for (int i = tid; i < 128 * 32; i += 256) {
      int r = i >> 5, c = (i & 31) << 2;
      *(u16x4*)&a_s[r * LDP + c] =
          *(const u16x4*)&u[(size_t)(chunk * 128 + r) * 256 + half * 128 + c];
      float4 g = *(const float4*)&f2w[(size_t)r * 256 + half * 128 + c];
      u16x4 hw = { f2bf(g.x), f2bf(g.y), f2bf(g.z), f2bf(g.w) };
      *(u16x4*)&w_s[r * LDP + c] = hw;
    }
    __syncthreads();
    mfma_tile_128(a_s, w_s, w, l15, lg, acc);
  }
#pragma unroll
  for (int mt = 0; mt < 2; ++mt)
#pragma unroll
    for (int r = 0; r < 4; ++r) {
      int m = w * 32 + mt * 16 + lg * 4 + r;
#pragma unroll
      for (int nt = 0; nt < 8; ++nt) {
        int n = nt * 16 + l15;
        float val = xc2[(size_t)(chunk * 128 + m) * HD + n] + acc[mt][nt][r] + f2b[n];
        out[(size_t)s_row[m] * HD + n] = val;
      }
    }
}

extern "C" void kernel_launch(void* const* d_in, const int* in_sizes, int n_in,
                              void* d_out, int out_size, void* d_ws, size_t ws_size,
                              hipStream_t stream) {
  const float* x    = (const float*)d_in[0];
  const float* ea   = (const float*)d_in[1];
  const float* We   = (const float*)d_in[2];
  const float* be   = (const float*)d_in[3];
  const float* W1   = (const float*)d_in[4];
  const float* b1   = (const float*)d_in[5];
  const float* W2   = (const float*)d_in[6];
  const float* b2   = (const float*)d_in[7];
  const float* g1   = (const float*)d_in[8];
  const float* bt1  = (const float*)d_in[9];
  const float* in_w = (const float*)d_in[10];
  const float* in_b = (const float*)d_in[11];
  const float* outw = (const float*)d_in[12];
  const float* outb = (const float*)d_in[13];
  const float* g2   = (const float*)d_in[14];
  const float* bt2  = (const float*)d_in[15];
  const float* f1w  = (const float*)d_in[16];
  const float* f1b  = (const float*)d_in[17];
  const float* f2w  = (const float*)d_in[18];
  const float* f2b  = (const float*)d_in[19];
  const void*  ei   = d_in[20];
  const void*  chem = d_in[21];
  const int N  = in_sizes[0] / HD;
  const int E  = in_sizes[1] / HD;
  const int NC = in_sizes[21];
  const int NB = (N + SCH - 1) / SCH;
  float* xo = (float*)d_out;

  char* ws = (char*)d_ws;
  size_t o = 0;
  auto alloc = [&](size_t bytes) { size_t p = o; o = (o + bytes + 255) & ~255ULL; return p; };
  size_t o_qkv  = alloc((size_t)NC * 384 * 4);
  size_t o_obuf = alloc((size_t)NC * 128 * 4);
  size_t o_xc2  = alloc((size_t)NC * 128 * 4);
  size_t o_h2b  = alloc((size_t)NC * 128 * 2);
  size_t o_ubuf = alloc((size_t)NC * 256 * 2);
  size_t o_flag = alloc(4);
  size_t o_webf = alloc(128 * 136 * 2);
  size_t o_w1b  = alloc(128 * 128 * 2);
  size_t o_w2b  = alloc(128 * 128 * 2);
  size_t o_xbf  = alloc((size_t)N * 128 * 2);
  size_t o_hbf  = alloc((size_t)N * 128 * 2);
  size_t o_deg  = alloc((size_t)N * 4);
  size_t o_off  = alloc((size_t)(N + 1) * 4);
  size_t o_cur  = alloc((size_t)N * 4);
  size_t o_bsum = alloc((size_t)NB * 4);
  size_t o_eid  = alloc((size_t)E * 4);
  size_t o_msg  = alloc((size_t)E * 128 * 2);
  size_t need = o;

  float*          qkv  = (float*)(ws + o_qkv);
  float*          obuf = (float*)(ws + o_obuf);
  float*          xc2  = (float*)(ws + o_xc2);
  unsigned short* h2b  = (unsigned short*)(ws + o_h2b);
  unsigned short* ubuf = (unsigned short*)(ws + o_ubuf);
  int*            flag = (int*)(ws + o_flag);
  unsigned short* webf = (unsigned short*)(ws + o_webf);
  unsigned short* w1b  = (unsigned short*)(ws + o_w1b);
  unsigned short* w2b  = (unsigned short*)(ws + o_w2b);
  unsigned short* xbf  = (unsigned short*)(ws + o_xbf);
  unsigned short* hbf  = (unsigned short*)(ws + o_hbf);
  int*            deg  = (int*)(ws + o_deg);
  int*            off  = (int*)(ws + o_off);
  int*            cur  = (int*)(ws + o_cur);
  int*            bsum = (int*)(ws + o_bsum);
  int*            eid  = (int*)(ws + o_eid);
  unsigned short* msg  = (unsigned short*)(ws + o_msg);

  detect_idx_kernel<<<1, 64, 0, stream>>>(ei, E, N, flag);

  if (ws_size >= need) {
    hipMemsetAsync(deg, 0, (size_t)N * 4, stream);
    conv_x_kernel<<<dim3((N * 16 + 255) / 256), 256, 0, stream>>>(x, xbf, (long long)N * 16);
    hist_kernel<<<dim3(1024), 256, 0, stream>>>(ei, flag, deg, E);
    scan_a<<<dim3(NB), 256, 0, stream>>>(deg, bsum, N);
    if (NB <= 128) scan_b2<<<1, 128, 0, stream>>>(bsum, off, NB, N);
    else           scan_b<<<1, 64, 0, stream>>>(bsum, off, NB, N);
    scan_c<<<dim3(NB), 256, 0, stream>>>(deg, bsum, off, cur, N);
    scatter_eid_kernel<<<dim3(1024), 256, 0, stream>>>(ei, flag, cur, eid, E);
    conv_we_kernel<<<dim3(64), 256, 0, stream>>>(We, webf);
    conv_w_kernel<<<dim3(64), 256, 0, stream>>>(W1, w1b, 128 * 128);
    conv_w_kernel<<<dim3(64), 256, 0, stream>>>(W2, w2b, 128 * 128);
    edge_kernel10<<<dim3((E + 127) / 128), 256, 0, stream>>>(xbf, ea, webf, be, ei,
                                                             flag, msg, E);
    gather_kernel10<<<dim3((N + 15) / 16), 256, 0, stream>>>(xbf, off, eid, msg, hbf, N);
    mlp_kernel<<<dim3((N + 127) / 128), 256, 0, stream>>>(x, xo, hbf, w1b, b1, w2b,
                                                          b2, g1, bt1, N);
  } else {
    hipMemsetAsync(xo, 0, (size_t)N * HD * sizeof(float), stream);
    edge_kernel<<<dim3((E + 127) / 128), 256, 0, stream>>>(x, ea, We, be, ei, flag, xo, E, N);
    node_kernel<<<dim3((N + 127) / 128), 256, 0, stream>>>(x, xo, W1, b1, W2, b2, g1, bt1, N);
  }

  const int ncs = NC / 128;
  qkv_kernel<<<dim3(ncs, 3), 256, 0, stream>>>(xo, in_w, in_b, chem, flag, qkv);
  attn_kernel<<<dim3(ncs, 4), 128, 0, stream>>>(qkv, obuf);
  oproj_kernel<<<dim3(ncs), 256, 0, stream>>>(xo, obuf, outw, outb, g2, bt2, chem, flag, xc2, h2b);
  ffn1_kernel<<<dim3(ncs, 2), 256, 0, stream>>>(h2b, f1w, f1b, ubuf);
  ffn2_kernel<<<dim3(ncs), 256, 0, stream>>>(ubuf, f2w, f2b, xc2, chem, flag, xo);
}

// Round 11
// 656.677 us; speedup vs baseline: 1.2231x; 1.2231x over previous
//
#include <hip/hip_runtime.h>
#include <hip/hip_bf16.h>
#include <math.h>

typedef __attribute__((ext_vector_type(8))) __bf16 bf16x8;
typedef __attribute__((ext_vector_type(4))) float f32x4;
typedef __attribute__((ext_vector_type(4))) unsigned short u16x4;

#define HD  128
#define LDP 136

__device__ __forceinline__ unsigned short f2bf(float f) {
  __bf16 h = (__bf16)f;
  union { __bf16 h; unsigned short u; } v; v.h = h; return v.u;
}
__device__ __forceinline__ float bf2f(unsigned short h) {
  union { unsigned u; float f; } v; v.u = ((unsigned)h) << 16; return v.f;
}

__device__ __forceinline__ int idx_at(const void* p, long long i, int is64) {
  if (is64) return (int)((const long long*)p)[i];
  return ((const int*)p)[i];
}

// 128x128 += A(LDS bf16 LDP) @ B^T(LDS bf16 LDP). wave w: rows [w*32,w*32+32)
// D: m = w*32+mt*16+(lane>>4)*4+r, n = nt*16+(lane&15)
__device__ __forceinline__ void mfma_tile_128(const unsigned short* a_s,
                                              const unsigned short* w_s,
                                              int w, int l15, int lg,
                                              f32x4 acc[2][8]) {
#pragma unroll
  for (int kk = 0; kk < 4; ++kk) {
    bf16x8 a[2], b[8];
#pragma unroll
    for (int mt = 0; mt < 2; ++mt)
      a[mt] = *(const bf16x8*)&a_s[(w * 32 + mt * 16 + l15) * LDP + kk * 32 + lg * 8];
#pragma unroll
    for (int nt = 0; nt < 8; ++nt)
      b[nt] = *(const bf16x8*)&w_s[(nt * 16 + l15) * LDP + kk * 32 + lg * 8];
#pragma unroll
    for (int mt = 0; mt < 2; ++mt)
#pragma unroll
      for (int nt = 0; nt < 8; ++nt)
        acc[mt][nt] = __builtin_amdgcn_mfma_f32_16x16x32_bf16(a[mt], b[nt], acc[mt][nt], 0, 0, 0);
  }
}

// B fragments from GLOBAL bf16 [128][ldw] (L2-hot weights)
__device__ __forceinline__ void mfma_tile_gb(const unsigned short* a_s,
                                             const unsigned short* Wb, int ldw,
                                             int w, int l15, int lg,
                                             f32x4 acc[2][8]) {
#pragma unroll
  for (int kk = 0; kk < 4; ++kk) {
    bf16x8 a[2], b[8];
#pragma unroll
    for (int mt = 0; mt < 2; ++mt)
      a[mt] = *(const bf16x8*)&a_s[(w * 32 + mt * 16 + l15) * LDP + kk * 32 + lg * 8];
#pragma unroll
    for (int nt = 0; nt < 8; ++nt)
      b[nt] = *(const bf16x8*)&Wb[(size_t)(nt * 16 + l15) * ldw + kk * 32 + lg * 8];
#pragma unroll
    for (int mt = 0; mt < 2; ++mt)
#pragma unroll
      for (int nt = 0; nt < 8; ++nt)
        acc[mt][nt] = __builtin_amdgcn_mfma_f32_16x16x32_bf16(a[mt], b[nt], acc[mt][nt], 0, 0, 0);
  }
}

__device__ __forceinline__ void stage_f32s(unsigned short* dst, const float* src,
                                           long long src_ld, int tid, int T) {
  for (int i = tid; i < 128 * 32; i += T) {
    int r = i >> 5, c = (i & 31) << 2;
    float4 f = *(const float4*)&src[(long long)r * src_ld + c];
    u16x4 h = { f2bf(f.x), f2bf(f.y), f2bf(f.z), f2bf(f.w) };
    *(u16x4*)&dst[r * LDP + c] = h;
  }
}

// ---------------- index dtype detector ----------------
__global__ void detect_idx_kernel(const void* __restrict__ ei, int E, int N,
                                  int* __restrict__ flag) {
  if (threadIdx.x == 0 && blockIdx.x == 0) {
    const long long* p = (const long long*)ei;
    int is64 = 1;
    long long step = E / 64; if (step < 1) step = 1;
    for (int i = 0; i < 64; ++i) {
      long long v = p[i * step];
      if (v < 0 || v >= N) { is64 = 0; break; }
    }
    *flag = is64;
  }
}

// ---------------- f32 -> bf16 pre-converts ----------------
__global__ __launch_bounds__(256) void conv_we_kernel(const float* __restrict__ We,
                                                      unsigned short* __restrict__ we_bf) {
  int i = blockIdx.x * 256 + threadIdx.x;
  if (i < 128 * 128) {
    int r = i >> 7, c = i & 127;
    we_bf[r * 136 + c] = f2bf(We[i]);
  }
}
// all dense weights in one launch: w1(16384) w2(16384) inw(49152) wo(16384) f1(32768) f2(32768)
__global__ __launch_bounds__(256) void conv_weights_kernel(
    const float* __restrict__ W1, const float* __restrict__ W2,
    const float* __restrict__ inw, const float* __restrict__ wo,
    const float* __restrict__ f1, const float* __restrict__ f2,
    unsigned short* __restrict__ w1b, unsigned short* __restrict__ w2b,
    unsigned short* __restrict__ inwb, unsigned short* __restrict__ wob,
    unsigned short* __restrict__ f1b, unsigned short* __restrict__ f2b) {
  int i = blockIdx.x * 256 + threadIdx.x;
  if (i < 16384) w1b[i] = f2bf(W1[i]);
  else if (i < 32768) w2b[i - 16384] = f2bf(W2[i - 16384]);
  else if (i < 81920) inwb[i - 32768] = f2bf(inw[i - 32768]);
  else if (i < 98304) wob[i - 81920] = f2bf(wo[i - 81920]);
  else if (i < 131072) f1b[i - 98304] = f2bf(f1[i - 98304]);
  else if (i < 163840) f2b[i - 131072] = f2bf(f2[i - 131072]);
}
__global__ __launch_bounds__(256) void conv_x_kernel(const float* __restrict__ x,
                                                     unsigned short* __restrict__ xb,
                                                     long long n8) {
  long long i = blockIdx.x * 256LL + threadIdx.x;
  if (i < n8) {
    float4 f0 = *(const float4*)&x[i * 8];
    float4 f1 = *(const float4*)&x[i * 8 + 4];
    u16x4 h0 = { f2bf(f0.x), f2bf(f0.y), f2bf(f0.z), f2bf(f0.w) };
    u16x4 h1 = { f2bf(f1.x), f2bf(f1.y), f2bf(f1.z), f2bf(f1.w) };
    *(u16x4*)&xb[i * 8] = h0;
    *(u16x4*)&xb[i * 8 + 4] = h1;
  }
}

// ---------------- dst histogram ----------------
__global__ __launch_bounds__(256) void hist_kernel(const void* __restrict__ ei,
                                                   const int* __restrict__ flag,
                                                   int* __restrict__ deg, int E) {
  const int is64 = *flag;
  for (long long e = blockIdx.x * 256LL + threadIdx.x; e < E;
       e += (long long)gridDim.x * 256)
    atomicAdd(&deg[idx_at(ei, (long long)E + e, is64)], 1);
}

// ---------------- 3-phase exclusive scan ----------------
#define SCH 1024
__global__ __launch_bounds__(256) void scan_a(const int* __restrict__ deg,
                                              int* __restrict__ bsum, int N) {
  const int b = blockIdx.x, t = threadIdx.x;
  int p = 0;
#pragma unroll
  for (int k = 0; k < 4; ++k) {
    int idx = b * SCH + t * 4 + k;
    if (idx < N) p += deg[idx];
  }
  __shared__ int warr[4];
  for (int o = 32; o > 0; o >>= 1) p += __shfl_xor(p, o);
  if ((t & 63) == 0) warr[t >> 6] = p;
  __syncthreads();
  if (t == 0) bsum[b] = warr[0] + warr[1] + warr[2] + warr[3];
}
__global__ void scan_b(int* __restrict__ bsum, int* __restrict__ off, int NB, int N) {
  if (threadIdx.x == 0 && blockIdx.x == 0) {
    int run = 0;
    for (int b = 0; b < NB; ++b) { int t = bsum[b]; bsum[b] = run; run += t; }
    off[N] = run;
  }
}
__global__ __launch_bounds__(128) void scan_b2(int* __restrict__ bsum,
                                               int* __restrict__ off, int NB, int N) {
  __shared__ int arr[128];
  const int t = threadIdx.x;
  int v = (t < NB) ? bsum[t] : 0;
  arr[t] = v;
  __syncthreads();
  for (int s = 1; s < 128; s <<= 1) {
    int u = (t >= s) ? arr[t - s] : 0;
    __syncthreads();
    arr[t] += u;
    __syncthreads();
  }
  if (t < NB) bsum[t] = arr[t] - v;
  if (t == 0) off[N] = arr[127];
}
__global__ __launch_bounds__(256) void scan_c(const int* __restrict__ deg,
                                              const int* __restrict__ bsum,
                                              int* __restrict__ off,
                                              int* __restrict__ cursor, int N) {
  const int b = blockIdx.x, t = threadIdx.x;
  int d[4], s = 0;
#pragma unroll
  for (int k = 0; k < 4; ++k) {
    int idx = b * SCH + t * 4 + k;
    d[k] = (idx < N) ? deg[idx] : 0;
    s += d[k];
  }
  __shared__ int arr[256];
  arr[t] = s;
  __syncthreads();
  for (int stp = 1; stp < 256; stp <<= 1) {
    int v = (t >= stp) ? arr[t - stp] : 0;
    __syncthreads();
    arr[t] += v;
    __syncthreads();
  }
  int base = bsum[b] + arr[t] - s;
  int acc = 0;
#pragma unroll
  for (int k = 0; k < 4; ++k) {
    int idx = b * SCH + t * 4 + k;
    if (idx < N) { off[idx] = base + acc; cursor[idx] = base + acc; }
    acc += d[k];
  }
}

// -------- edge kernel (r9 winner): streaming A->regs, bf16 We, CSR msg writes ------
__global__ __launch_bounds__(256, 4) void edge_kernel9(
    const unsigned short* __restrict__ x_bf, const float* __restrict__ ea,
    const unsigned short* __restrict__ we_bf, const float* __restrict__ be,
    const void* __restrict__ ei, const int* __restrict__ flag,
    int* __restrict__ cursor, unsigned short* __restrict__ msg, int E) {
  __shared__ unsigned short we_s[128 * LDP];
  __shared__ int s_src[128];
  __shared__ int s_pos[128];
  const int tid = threadIdx.x;
  const long long e0 = (long long)blockIdx.x * 128;
  const int is64 = *flag;

  if (tid < 128) {
    long long e = e0 + tid;
    int s = 0, p = 0;
    if (e < E) {
      s = idx_at(ei, e, is64);
      int d = idx_at(ei, (long long)E + e, is64);
      p = atomicAdd(&cursor[d], 1);
    }
    s_src[tid] = s; s_pos[tid] = p;
  }

  const int lane = tid & 63, w = tid >> 6;
  const int l15 = lane & 15, lg = lane >> 4;

  float4 af[2][4][2];
#pragma unroll
  for (int mt = 0; mt < 2; ++mt) {
    long long row = e0 + w * 32 + mt * 16 + l15;
    const float* src = &ea[(row < E ? row : e0) * HD + lg * 8];
#pragma unroll
    for (int kk = 0; kk < 4; ++kk) {
      af[mt][kk][0] = *(const float4*)&src[kk * 32];
      af[mt][kk][1] = *(const float4*)&src[kk * 32 + 4];
    }
  }

  for (int i = tid; i < 2048; i += 256) {
    int r = i >> 4, c = (i & 15) << 3;
    *(float4*)&we_s[r * LDP + c] = *(const float4*)&we_bf[r * 136 + c];
  }

  bf16x8 a[2][4];
#pragma unroll
  for (int mt = 0; mt < 2; ++mt)
#pragma unroll
    for (int kk = 0; kk < 4; ++kk) {
      float4 f0 = af[mt][kk][0], f1 = af[mt][kk][1];
      bf16x8 t;
      t[0] = (__bf16)f0.x; t[1] = (__bf16)f0.y; t[2] = (__bf16)f0.z; t[3] = (__bf16)f0.w;
      t[4] = (__bf16)f1.x; t[5] = (__bf16)f1.y; t[6] = (__bf16)f1.z; t[7] = (__bf16)f1.w;
      a[mt][kk] = t;
    }
  __syncthreads();

  f32x4 acc[2][8];
#pragma unroll
  for (int mt = 0; mt < 2; ++mt)
#pragma unroll
    for (int nt = 0; nt < 8; ++nt) acc[mt][nt] = (f32x4){0.f, 0.f, 0.f, 0.f};

#pragma unroll
  for (int kk = 0; kk < 4; ++kk) {
    bf16x8 b[8];
#pragma unroll
    for (int nt = 0; nt < 8; ++nt)
      b[nt] = *(const bf16x8*)&we_s[(nt * 16 + l15) * LDP + kk * 32 + lg * 8];
#pragma unroll
    for (int mt = 0; mt < 2; ++mt)
#pragma unroll
      for (int nt = 0; nt < 8; ++nt)
        acc[mt][nt] = __builtin_amdgcn_mfma_f32_16x16x32_bf16(a[mt][kk], b[nt], acc[mt][nt], 0, 0, 0);
  }

  float bev[8];
#pragma unroll
  for (int nt = 0; nt < 8; ++nt) bev[nt] = be[nt * 16 + l15];
  __syncthreads();

#pragma unroll
  for (int mt = 0; mt < 2; ++mt)
#pragma unroll
    for (int r = 0; r < 4; ++r) {
      int m = w * 32 + mt * 16 + lg * 4 + r;
#pragma unroll
      for (int nt = 0; nt < 8; ++nt)
        we_s[m * LDP + nt * 16 + l15] = f2bf(acc[mt][nt][r] + bev[nt]);
    }
  __syncthreads();

  for (int i = tid; i < 128 * 16; i += 256) {
    int r = i >> 4, sg = i & 15;
    if (e0 + r >= E) continue;
    bf16x8 xv = *(const bf16x8*)&x_bf[(size_t)s_src[r] * HD + sg * 8];
    bf16x8 g = *(const bf16x8*)&we_s[r * LDP + sg * 8];
    u16x4 h0, h1;
#pragma unroll
    for (int k = 0; k < 4; ++k) {
      float v = (float)g[k] + (float)xv[k];
      h0[k] = f2bf(v > 0.f ? v : 0.f);
    }
#pragma unroll
    for (int k = 0; k < 4; ++k) {
      float v = (float)g[4 + k] + (float)xv[4 + k];
      h1[k] = f2bf(v > 0.f ? v : 0.f);
    }
    unsigned short* mp = &msg[(size_t)s_pos[r] * 128 + sg * 8];
    *(u16x4*)&mp[0] = h0;
    *(u16x4*)&mp[4] = h1;
  }
}

// -------- gather kernel (r9 winner): sequential segment reads -------------
__global__ __launch_bounds__(256) void gather_kernel(
    const unsigned short* __restrict__ x_bf, const int* __restrict__ off,
    const unsigned short* __restrict__ msg, unsigned short* __restrict__ h_bf,
    int N) {
  const int tid = threadIdx.x;
  const int grp = tid >> 4, li = tid & 15;
  const long long row = (long long)blockIdx.x * 16 + grp;
  if (row >= N) return;
  const int co = li * 8;
  float a8[8];
  bf16x8 xv = *(const bf16x8*)&x_bf[row * HD + co];
#pragma unroll
  for (int k = 0; k < 8; ++k) a8[k] = (float)xv[k];
  const int j0 = off[row], j1 = off[row + 1];
  int j = j0;
  for (; j + 3 < j1; j += 4) {
    bf16x8 v0 = *(const bf16x8*)&msg[(size_t)j * 128 + co];
    bf16x8 v1 = *(const bf16x8*)&msg[(size_t)(j + 1) * 128 + co];
    bf16x8 v2 = *(const bf16x8*)&msg[(size_t)(j + 2) * 128 + co];
    bf16x8 v3 = *(const bf16x8*)&msg[(size_t)(j + 3) * 128 + co];
#pragma unroll
    for (int k = 0; k < 8; ++k)
      a8[k] += ((float)v0[k] + (float)v1[k]) + ((float)v2[k] + (float)v3[k]);
  }
  for (; j < j1; ++j) {
    bf16x8 v0 = *(const bf16x8*)&msg[(size_t)j * 128 + co];
#pragma unroll
    for (int k = 0; k < 8; ++k) a8[k] += (float)v0[k];
  }
  bf16x8 hv;
#pragma unroll
  for (int k = 0; k < 8; ++k) hv[k] = (__bf16)a8[k];
  *(bf16x8*)&h_bf[row * HD + co] = hv;
}

// -------- mlp kernel: xo = LN1(x + mlp(h)) -------------------
__global__ __launch_bounds__(256, 4) void mlp_kernel(
    const float* __restrict__ x, float* __restrict__ xo,
    const unsigned short* __restrict__ h_bf,
    const unsigned short* __restrict__ W1b, const float* __restrict__ b1,
    const unsigned short* __restrict__ W2b, const float* __restrict__ b2,
    const float* __restrict__ g1, const float* __restrict__ bt1, int N) {
  __shared__ unsigned short a_s[128 * LDP];
  const int tid = threadIdx.x;
  const long long r0 = (long long)blockIdx.x * 128;

  for (int i = tid; i < 2048; i += 256) {
    int r = i >> 4, c = (i & 15) << 3;
    long long gr = r0 + r;
    bf16x8 v;
    if (gr < N) v = *(const bf16x8*)&h_bf[gr * HD + c];
    else {
#pragma unroll
      for (int k = 0; k < 8; ++k) v[k] = (__bf16)0.f;
    }
    *(bf16x8*)&a_s[r * LDP + c] = v;
  }
  __syncthreads();

  const int lane = tid & 63, w = tid >> 6;
  const int l15 = lane & 15, lg = lane >> 4;
  f32x4 acc[2][8];
#pragma unroll
  for (int mt = 0; mt < 2; ++mt)
#pragma unroll
    for (int nt = 0; nt < 8; ++nt) acc[mt][nt] = (f32x4){0.f, 0.f, 0.f, 0.f};
  mfma_tile_gb(a_s, W1b, 128, w, l15, lg, acc);
  __syncthreads();

#pragma unroll
  for (int mt = 0; mt < 2; ++mt)
#pragma unroll
    for (int r = 0; r < 4; ++r) {
      int m = w * 32 + mt * 16 + lg * 4 + r;
#pragma unroll
      for (int nt = 0; nt < 8; ++nt) {
        int n = nt * 16 + l15;
        float t = acc[mt][nt][r] + b1[n];
        a_s[m * LDP + n] = f2bf(t > 0.f ? t : 0.f);
      }
    }
  __syncthreads();

  f32x4 acc2[2][8];
#pragma unroll
  for (int mt = 0; mt < 2; ++mt)
#pragma unroll
    for (int nt = 0; nt < 8; ++nt) acc2[mt][nt] = (f32x4){0.f, 0.f, 0.f, 0.f};
  mfma_tile_gb(a_s, W2b, 128, w, l15, lg, acc2);
  __syncthreads();

#pragma unroll
  for (int mt = 0; mt < 2; ++mt)
#pragma unroll
    for (int r = 0; r < 4; ++r) {
      int m = w * 32 + mt * 16 + lg * 4 + r;
      if (r0 + m < N) {
#pragma unroll
        for (int nt = 0; nt < 8; ++nt) {
          int n = nt * 16 + l15;
          a_s[m * LDP + n] = f2bf(x[(r0 + m) * HD + n] + acc2[mt][nt][r] + b2[n]);
        }
      }
    }
  __syncthreads();

  for (int row = w; row < 128; row += 4) {
    if (r0 + row >= N) continue;
    float v1 = bf2f(a_s[row * LDP + lane]), v2 = bf2f(a_s[row * LDP + 64 + lane]);
    float s = v1 + v2, sq = v1 * v1 + v2 * v2;
    for (int o = 32; o > 0; o >>= 1) { s += __shfl_xor(s, o); sq += __shfl_xor(sq, o); }
    float mean = s * (1.f / 128.f);
    float var = sq * (1.f / 128.f) - mean * mean;
    float rs = rsqrtf(var + 1e-5f);
    xo[(r0 + row) * HD + lane]      = (v1 - mean) * rs * g1[lane] + bt1[lane];
    xo[(r0 + row) * HD + 64 + lane] = (v2 - mean) * rs * g1[lane + 64] + bt1[lane + 64];
  }
}

// ======== FUSED chem kernel: qkv -> 4-head attn -> oproj+LN2 -> ffn1 -> ffn2 ======
// One block per chunk (128 rows). All GEMM-output->GEMM-input transits are
// intra-wave (each wave owns rows [w*32, w*32+32) throughout).
__global__ __launch_bounds__(256) void chem_kernel(
    float* __restrict__ xo,                 // read xc rows; write final rows
    const unsigned short* __restrict__ inwb, const float* __restrict__ in_b,
    const unsigned short* __restrict__ wob, const float* __restrict__ bo,
    const float* __restrict__ g2, const float* __restrict__ bt2,
    const unsigned short* __restrict__ f1wb, const float* __restrict__ f1b,
    const unsigned short* __restrict__ f2wb, const float* __restrict__ f2b,
    const void* __restrict__ chem, const int* __restrict__ flag) {
  __shared__ unsigned short xc_s[128 * LDP];  // xc -> P -> h2
  __shared__ unsigned short q_s[128 * LDP];   // q  -> O -> u[0:128]
  __shared__ unsigned short k_s[128 * LDP];   // k  -> y stash (bf16)
  __shared__ unsigned short vt_s[128 * LDP];  // v^T -> u[128:256]
  __shared__ int s_row[128];
  const int tid = threadIdx.x, chunk = blockIdx.x;
  const int is64 = *flag;
  if (tid < 128) s_row[tid] = idx_at(chem, (long long)chunk * 128 + tid, is64);
  __syncthreads();

  // stage xc (f32 -> bf16)
  for (int i = tid; i < 2048; i += 256) {
    int r = i >> 4, c = (i & 15) << 3;
    const float* src = &xo[(size_t)s_row[r] * HD + c];
    float4 f0 = *(const float4*)&src[0];
    float4 f1 = *(const float4*)&src[4];
    u16x4 h0 = { f2bf(f0.x), f2bf(f0.y), f2bf(f0.z), f2bf(f0.w) };
    u16x4 h1 = { f2bf(f1.x), f2bf(f1.y), f2bf(f1.z), f2bf(f1.w) };
    *(u16x4*)&xc_s[r * LDP + c] = h0;
    *(u16x4*)&xc_s[r * LDP + c + 4] = h1;
  }
  __syncthreads();

  const int lane = tid & 63, w = tid >> 6;
  const int l15 = lane & 15, lg = lane >> 4;
  const float scale = 0.1767766952966369f;  // 1/sqrt(32), folded into q

  // ---- qkv (3 GEMMs, B from global bf16) ----
  for (int sec = 0; sec < 3; ++sec) {
    f32x4 acc[2][8];
#pragma unroll
    for (int mt = 0; mt < 2; ++mt)
#pragma unroll
      for (int nt = 0; nt < 8; ++nt) acc[mt][nt] = (f32x4){0.f, 0.f, 0.f, 0.f};
    mfma_tile_gb(xc_s, inwb + (size_t)sec * 128 * 128, 128, w, l15, lg, acc);
#pragma unroll
    for (int mt = 0; mt < 2; ++mt)
#pragma unroll
      for (int r = 0; r < 4; ++r) {
        int m = w * 32 + mt * 16 + lg * 4 + r;
#pragma unroll
        for (int nt = 0; nt < 8; ++nt) {
          int n = nt * 16 + l15;
          float t = acc[mt][nt][r] + in_b[sec * 128 + n];
          if (sec == 0)      q_s[m * LDP + n] = f2bf(t * scale);
          else if (sec == 1) k_s[m * LDP + n] = f2bf(t);
          else               vt_s[n * LDP + m] = f2bf(t);   // transposed store
        }
      }
  }
  __syncthreads();  // k_s / vt_s are read cross-wave below

  // ---- 4-head attention; O accumulates in acc[2][8] (head h -> nt tiles 2h,2h+1)
  f32x4 oacc[2][8];
#pragma unroll
  for (int mt = 0; mt < 2; ++mt)
#pragma unroll
    for (int nt = 0; nt < 8; ++nt) oacc[mt][nt] = (f32x4){0.f, 0.f, 0.f, 0.f};

  for (int h = 0; h < 4; ++h) {
    // S = q_h @ k_h^T (K=32, single MFMA step)
    f32x4 sacc[2][8];
#pragma unroll
    for (int mt = 0; mt < 2; ++mt)
#pragma unroll
      for (int nt = 0; nt < 8; ++nt) sacc[mt][nt] = (f32x4){0.f, 0.f, 0.f, 0.f};
    {
      bf16x8 a[2], b[8];
#pragma unroll
      for (int mt = 0; mt < 2; ++mt)
        a[mt] = *(const bf16x8*)&q_s[(w * 32 + mt * 16 + l15) * LDP + h * 32 + lg * 8];
#pragma unroll
      for (int nt = 0; nt < 8; ++nt)
        b[nt] = *(const bf16x8*)&k_s[(nt * 16 + l15) * LDP + h * 32 + lg * 8];
#pragma unroll
      for (int mt = 0; mt < 2; ++mt)
#pragma unroll
        for (int nt = 0; nt < 8; ++nt)
          sacc[mt][nt] = __builtin_amdgcn_mfma_f32_16x16x32_bf16(a[mt], b[nt], sacc[mt][nt], 0, 0, 0);
    }
    // row softmax (row spread over l15 lanes x 8 nt) -> P bf16 into xc_s
#pragma unroll
    for (int mt = 0; mt < 2; ++mt)
#pragma unroll
      for (int r = 0; r < 4; ++r) {
        int m = w * 32 + mt * 16 + lg * 4 + r;
        float mx = -1e30f;
#pragma unroll
        for (int nt = 0; nt < 8; ++nt) mx = fmaxf(mx, sacc[mt][nt][r]);
        for (int o = 8; o > 0; o >>= 1) mx = fmaxf(mx, __shfl_xor(mx, o));
        float sm = 0.f;
        float p[8];
#pragma unroll
        for (int nt = 0; nt < 8; ++nt) { p[nt] = __expf(sacc[mt][nt][r] - mx); sm += p[nt]; }
        for (int o = 8; o > 0; o >>= 1) sm += __shfl_xor(sm, o);
        float inv = 1.f / sm;
#pragma unroll
        for (int nt = 0; nt < 8; ++nt)
          xc_s[m * LDP + nt * 16 + l15] = f2bf(p[nt] * inv);
      }
    // O_h = P @ V_h : A = P (intra-wave rows), B = vt rows h*32+nt2*16+l15
#pragma unroll
    for (int kk = 0; kk < 4; ++kk) {
      bf16x8 pa[2], vb[2];
#pragma unroll
      for (int mt = 0; mt < 2; ++mt)
        pa[mt] = *(const bf16x8*)&xc_s[(w * 32 + mt * 16 + l15) * LDP + kk * 32 + lg * 8];
#pragma unroll
      for (int nt2 = 0; nt2 < 2; ++nt2)
        vb[nt2] = *(const bf16x8*)&vt_s[(h * 32 + nt2 * 16 + l15) * LDP + kk * 32 + lg * 8];
#pragma unroll
      for (int mt = 0; mt < 2; ++mt)
#pragma unroll
        for (int nt2 = 0; nt2 < 2; ++nt2)
          oacc[mt][h * 2 + nt2] =
              __builtin_amdgcn_mfma_f32_16x16x32_bf16(pa[mt], vb[nt2], oacc[mt][h * 2 + nt2], 0, 0, 0);
    }
  }
  __syncthreads();  // k_s / vt_s cross-wave reads done -> safe to reuse

  // O -> q_s (band-own)
#pragma unroll
  for (int mt = 0; mt < 2; ++mt)
#pragma unroll
    for (int r = 0; r < 4; ++r) {
      int m = w * 32 + mt * 16 + lg * 4 + r;
#pragma unroll
      for (int nt = 0; nt < 8; ++nt)
        q_s[m * LDP + nt * 16 + l15] = f2bf(oacc[mt][nt][r]);
    }

  // ---- oproj + residual + LN2 ----
  f32x4 pacc[2][8];
#pragma unroll
  for (int mt = 0; mt < 2; ++mt)
#pragma unroll
    for (int nt = 0; nt < 8; ++nt) pacc[mt][nt] = (f32x4){0.f, 0.f, 0.f, 0.f};
  mfma_tile_gb(q_s, wob, 128, w, l15, lg, pacc);

#pragma unroll
  for (int mt = 0; mt < 2; ++mt)
#pragma unroll
    for (int r = 0; r < 4; ++r) {
      int m = w * 32 + mt * 16 + lg * 4 + r;
      const float* xrow = &xo[(size_t)s_row[m] * HD];
      float y[8];
      float s = 0.f, sq = 0.f;
#pragma unroll
      for (int nt = 0; nt < 8; ++nt) {
        int n = nt * 16 + l15;
        y[nt] = xrow[n] + pacc[mt][nt][r] + bo[n];
        s += y[nt]; sq += y[nt] * y[nt];
      }
      for (int o = 8; o > 0; o >>= 1) { s += __shfl_xor(s, o); sq += __shfl_xor(sq, o); }
      float mean = s * (1.f / 128.f);
      float var = sq * (1.f / 128.f) - mean * mean;
      float rs = rsqrtf(var + 1e-5f);
#pragma unroll
      for (int nt = 0; nt < 8; ++nt) {
        int n = nt * 16 + l15;
        xc_s[m * LDP + n] = f2bf((y[nt] - mean) * rs * g2[n] + bt2[n]);  // h2
        k_s[m * LDP + n]  = f2bf(y[nt]);                                 // y stash
      }
    }

  // ---- ffn1: u = relu(h2 @ f1w^T + f1b), 2 sections -> q_s / vt_s ----
  for (int sec = 0; sec < 2; ++sec) {
    f32x4 acc[2][8];
#pragma unroll
    for (int mt = 0; mt < 2; ++mt)
#pragma unroll
      for (int nt = 0; nt < 8; ++nt) acc[mt][nt] = (f32x4){0.f, 0.f, 0.f, 0.f};
    mfma_tile_gb(xc_s, f1wb + (size_t)sec * 128 * 128, 128, w, l15, lg, acc);
    unsigned short* ub = (sec == 0) ? q_s : vt_s;
#pragma unroll
    for (int mt = 0; mt < 2; ++mt)
#pragma unroll
      for (int r = 0; r < 4; ++r) {
        int m = w * 32 + mt * 16 + lg * 4 + r;
#pragma unroll
        for (int nt = 0; nt < 8; ++nt) {
          int n = nt * 16 + l15;
          float t = acc[mt][nt][r] + f1b[sec * 128 + n];
          ub[m * LDP + n] = f2bf(t > 0.f ? t : 0.f);
        }
      }
  }

  // ---- ffn2: out = y + u @ f2w^T + f2b (K=256) ----
  f32x4 facc[2][8];
#pragma unroll
  for (int mt = 0; mt < 2; ++mt)
#pragma unroll
    for (int nt = 0; nt < 8; ++nt) facc[mt][nt] = (f32x4){0.f, 0.f, 0.f, 0.f};
  mfma_tile_gb(q_s, f2wb, 256, w, l15, lg, facc);
  mfma_tile_gb(vt_s, f2wb + 128, 256, w, l15, lg, facc);

#pragma unroll
  for (int mt = 0; mt < 2; ++mt)
#pragma unroll
    for (int r = 0; r < 4; ++r) {
      int m = w * 32 + mt * 16 + lg * 4 + r;
      float* orow = &xo[(size_t)s_row[m] * HD];
#pragma unroll
      for (int nt = 0; nt < 8; ++nt) {
        int n = nt * 16 + l15;
        orow[n] = bf2f(k_s[m * LDP + n]) + facc[mt][nt][r] + f2b[n];
      }
    }
}

// ================= FALLBACK (small ws): atomic edge + fused node =================
__global__ __launch_bounds__(256) void edge_kernel(
    const float* __restrict__ x, const float* __restrict__ ea,
    const float* __restrict__ We, const float* __restrict__ be,
    const void* __restrict__ ei, const int* __restrict__ flag,
    float* __restrict__ agg, int E, int N) {
  __shared__ unsigned short ea_s[128 * LDP];
  __shared__ unsigned short we_s[128 * LDP];
  __shared__ int s_src[128];
  __shared__ int s_dst[128];
  const int tid = threadIdx.x;
  const long long e0 = (long long)blockIdx.x * 128;
  const int is64 = *flag;
  if (tid < 128) {
    long long e = e0 + tid;
    int s = 0, d = 0;
    if (e < E) { s = idx_at(ei, e, is64); d = idx_at(ei, (long long)E + e, is64); }
    s_src[tid] = s; s_dst[tid] = d;
  }
  for (int i = tid; i < 128 * 32; i += 256) {
    int r = i >> 5, c = (i & 31) << 2;
    float4 f = {0.f, 0.f, 0.f, 0.f};
    if (e0 + r < E) f = *(const float4*)&ea[(e0 + r) * HD + c];
    u16x4 h = { f2bf(f.x), f2bf(f.y), f2bf(f.z), f2bf(f.w) };
    *(u16x4*)&ea_s[r * LDP + c] = h;
    float4 g = *(const float4*)&We[r * HD + c];
    u16x4 hw = { f2bf(g.x), f2bf(g.y), f2bf(g.z), f2bf(g.w) };
    *(u16x4*)&we_s[r * LDP + c] = hw;
  }
  __syncthreads();
  const int lane = tid & 63, w = tid >> 6;
  const int l15 = lane & 15, lg = lane >> 4;
  f32x4 acc[2][8];
#pragma unroll
  for (int mt = 0; mt < 2; ++mt)
#pragma unroll
    for (int nt = 0; nt < 8; ++nt) acc[mt][nt] = (f32x4){0.f, 0.f, 0.f, 0.f};
  mfma_tile_128(ea_s, we_s, w, l15, lg, acc);
  float bev[8];
#pragma unroll
  for (int nt = 0; nt < 8; ++nt) bev[nt] = be[nt * 16 + l15];
#pragma unroll
  for (int mt = 0; mt < 2; ++mt) {
#pragma unroll
    for (int r = 0; r < 4; ++r) {
      int m = w * 32 + mt * 16 + lg * 4 + r;
      if (e0 + m >= E) continue;
      const float* xrow = x + (size_t)s_src[m] * HD;
      float* arow = agg + (size_t)s_dst[m] * HD;
#pragma unroll
      for (int nt = 0; nt < 8; ++nt) {
        int n = nt * 16 + l15;
        float val = acc[mt][nt][r] + bev[nt] + xrow[n];
        if (val > 0.f) unsafeAtomicAdd(&arow[n], val);
      }
    }
  }
}

__global__ __launch_bounds__(256) void node_kernel(
    const float* __restrict__ x, float* xo,
    const float* __restrict__ W1, const float* __restrict__ b1,
    const float* __restrict__ W2, const float* __restrict__ b2,
    const float* __restrict__ g1, const float* __restrict__ bt1, int N) {
  __shared__ char smem[2 * 128 * LDP * 2];
  unsigned short* a_s = (unsigned short*)smem;
  unsigned short* w_s = (unsigned short*)smem + 128 * LDP;
  float* y_s = (float*)smem;
  const int tid = threadIdx.x;
  const long long r0 = (long long)blockIdx.x * 128;
  for (int i = tid; i < 128 * 32; i += 256) {
    int r = i >> 5, c = (i & 31) << 2;
    float4 f = {0.f, 0.f, 0.f, 0.f};
    if (r0 + r < N) {
      float4 xa = *(const float4*)&x[(r0 + r) * HD + c];
      float4 ag = *(const float4*)&xo[(r0 + r) * HD + c];
      f.x = xa.x + ag.x; f.y = xa.y + ag.y; f.z = xa.z + ag.z; f.w = xa.w + ag.w;
    }
    u16x4 h = { f2bf(f.x), f2bf(f.y), f2bf(f.z), f2bf(f.w) };
    *(u16x4*)&a_s[r * LDP + c] = h;
    float4 g = *(const float4*)&W1[r * HD + c];
    u16x4 hw = { f2bf(g.x), f2bf(g.y), f2bf(g.z), f2bf(g.w) };
    *(u16x4*)&w_s[r * LDP + c] = hw;
  }
  __syncthreads();
  const int lane = tid & 63, w = tid >> 6;
  const int l15 = lane & 15, lg = lane >> 4;
  f32x4 acc[2][8];
#pragma unroll
  for (int mt = 0; mt < 2; ++mt)
#pragma unroll
    for (int nt = 0; nt < 8; ++nt) acc[mt][nt] = (f32x4){0.f, 0.f, 0.f, 0.f};
  mfma_tile_128(a_s, w_s, w, l15, lg, acc);
  __syncthreads();
#pragma unroll
  for (int mt = 0; mt < 2; ++mt)
#pragma unroll
    for (int r = 0; r < 4; ++r) {
      int m = w * 32 + mt * 16 + lg * 4 + r;
#pragma unroll
      for (int nt = 0; nt < 8; ++nt) {
        int n = nt * 16 + l15;
        float t = acc[mt][nt][r] + b1[n];
        a_s[m * LDP + n] = f2bf(t > 0.f ? t : 0.f);
      }
    }
  stage_f32s(w_s, W2, HD, tid, 256);
  __syncthreads();
  f32x4 acc2[2][8];
#pragma unroll
  for (int mt = 0; mt < 2; ++mt)
#pragma unroll
    for (int nt = 0; nt < 8; ++nt) acc2[mt][nt] = (f32x4){0.f, 0.f, 0.f, 0.f};
  mfma_tile_128(a_s, w_s, w, l15, lg, acc2);
  __syncthreads();
#pragma unroll
  for (int mt = 0; mt < 2; ++mt)
#pragma unroll
    for (int r = 0; r < 4; ++r) {
      int m = w * 32 + mt * 16 + lg * 4 + r;
      if (r0 + m < N) {
#pragma unroll
        for (int nt = 0; nt < 8; ++nt) {
          int n = nt * 16 + l15;
          y_s[m * 132 + n] = x[(r0 + m) * HD + n] + acc2[mt][nt][r] + b2[n];
        }
      }
    }
  __syncthreads();
  for (int row = w; row < 128; row += 4) {
    if (r0 + row >= N) continue;
    float v1 = y_s[row * 132 + lane], v2 = y_s[row * 132 + 64 + lane];
    float s = v1 + v2, sq = v1 * v1 + v2 * v2;
    for (int o = 32; o > 0; o >>= 1) { s += __shfl_xor(s, o); sq += __shfl_xor(sq, o); }
    float mean = s * (1.f / 128.f);
    float var = sq * (1.f / 128.f) - mean * mean;
    float rs = rsqrtf(var + 1e-5f);
    xo[(r0 + row) * HD + lane]      = (v1 - mean) * rs * g1[lane] + bt1[lane];
    xo[(r0 + row) * HD + 64 + lane] = (v2 - mean) * rs * g1[lane + 64] + bt1[lane + 64];
  }
}

extern "C" void kernel_launch(void* const* d_in, const int* in_sizes, int n_in,
                              void* d_out, int out_size, void* d_ws, size_t ws_size,
                              hipStream_t stream) {
  const float* x    = (const float*)d_in[0];
  const float* ea   = (const float*)d_in[1];
  const float* We   = (const float*)d_in[2];
  const float* be   = (const float*)d_in[3];
  const float* W1   = (const float*)d_in[4];
  const float* b1   = (const float*)d_in[5];
  const float* W2   = (const float*)d_in[6];
  const float* b2   = (const float*)d_in[7];
  const float* g1   = (const float*)d_in[8];
  const float* bt1  = (const float*)d_in[9];
  const float* in_w = (const float*)d_in[10];
  const float* in_b = (const float*)d_in[11];
  const float* outw = (const float*)d_in[12];
  const float* outb = (const float*)d_in[13];
  const float* g2   = (const float*)d_in[14];
  const float* bt2  = (const float*)d_in[15];
  const float* f1w  = (const float*)d_in[16];
  const float* f1b  = (const float*)d_in[17];
  const float* f2w  = (const float*)d_in[18];
  const float* f2b  = (const float*)d_in[19];
  const void*  ei   = d_in[20];
  const void*  chem = d_in[21];
  const int N  = in_sizes[0] / HD;
  const int E  = in_sizes[1] / HD;
  const int NC = in_sizes[21];
  const int NB = (N + SCH - 1) / SCH;
  float* xo = (float*)d_out;

  char* ws = (char*)d_ws;
  size_t o = 0;
  auto alloc = [&](size_t bytes) { size_t p = o; o = (o + bytes + 255) & ~255ULL; return p; };
  // small region first (weights; needed by both paths)
  size_t o_flag = alloc(4);
  size_t o_webf = alloc(128 * 136 * 2);
  size_t o_w1b  = alloc(128 * 128 * 2);
  size_t o_w2b  = alloc(128 * 128 * 2);
  size_t o_inwb = alloc(384 * 128 * 2);
  size_t o_wob  = alloc(128 * 128 * 2);
  size_t o_f1wb = alloc(256 * 128 * 2);
  size_t o_f2wb = alloc(128 * 256 * 2);
  // large region (CSR pipeline)
  size_t o_xbf  = alloc((size_t)N * 128 * 2);
  size_t o_hbf  = alloc((size_t)N * 128 * 2);
  size_t o_deg  = alloc((size_t)N * 4);
  size_t o_off  = alloc((size_t)(N + 1) * 4);
  size_t o_cur  = alloc((size_t)N * 4);
  size_t o_bsum = alloc((size_t)NB * 4);
  size_t o_msg  = alloc((size_t)E * 128 * 2);
  size_t need = o;

  int*            flag = (int*)(ws + o_flag);
  unsigned short* webf = (unsigned short*)(ws + o_webf);
  unsigned short* w1b  = (unsigned short*)(ws + o_w1b);
  unsigned short* w2b  = (unsigned short*)(ws + o_w2b);
  unsigned short* inwb = (unsigned short*)(ws + o_inwb);
  unsigned short* wob  = (unsigned short*)(ws + o_wob);
  unsigned short* f1wb = (unsigned short*)(ws + o_f1wb);
  unsigned short* f2wb = (unsigned short*)(ws + o_f2wb);
  unsigned short* xbf  = (unsigned short*)(ws + o_xbf);
  unsigned short* hbf  = (unsigned short*)(ws + o_hbf);
  int*            deg  = (int*)(ws + o_deg);
  int*            off  = (int*)(ws + o_off);
  int*            cur  = (int*)(ws + o_cur);
  int*            bsum = (int*)(ws + o_bsum);
  unsigned short* msg  = (unsigned short*)(ws + o_msg);

  detect_idx_kernel<<<1, 64, 0, stream>>>(ei, E, N, flag);
  conv_weights_kernel<<<dim3(640), 256, 0, stream>>>(W1, W2, in_w, outw, f1w, f2w,
                                                     w1b, w2b, inwb, wob, f1wb, f2wb);

  if (ws_size >= need) {
    hipMemsetAsync(deg, 0, (size_t)N * 4, stream);
    conv_x_kernel<<<dim3((N * 16 + 255) / 256), 256, 0, stream>>>(x, xbf, (long long)N * 16);
    hist_kernel<<<dim3(1024), 256, 0, stream>>>(ei, flag, deg, E);
    scan_a<<<dim3(NB), 256, 0, stream>>>(deg, bsum, N);
    if (NB <= 128) scan_b2<<<1, 128, 0, stream>>>(bsum, off, NB, N);
    else           scan_b<<<1, 64, 0, stream>>>(bsum, off, NB, N);
    scan_c<<<dim3(NB), 256, 0, stream>>>(deg, bsum, off, cur, N);
    conv_we_kernel<<<dim3(64), 256, 0, stream>>>(We, webf);
    edge_kernel9<<<dim3((E + 127) / 128), 256, 0, stream>>>(xbf, ea, webf, be, ei,
                                                            flag, cur, msg, E);
    gather_kernel<<<dim3((N + 15) / 16), 256, 0, stream>>>(xbf, off, msg, hbf, N);
    mlp_kernel<<<dim3((N + 127) / 128), 256, 0, stream>>>(x, xo, hbf, w1b, b1, w2b,
                                                          b2, g1, bt1, N);
  } else {
    hipMemsetAsync(xo, 0, (size_t)N * HD * sizeof(float), stream);
    edge_kernel<<<dim3((E + 127) / 128), 256, 0, stream>>>(x, ea, We, be, ei, flag, xo, E, N);
    node_kernel<<<dim3((N + 127) / 128), 256, 0, stream>>>(x, xo, W1, b1, W2, b2, g1, bt1, N);
  }

  chem_kernel<<<dim3(NC / 128), 256, 0, stream>>>(xo, inwb, in_b, wob, outb, g2, bt2,
                                                  f1wb, f1b, f2wb, f2b, chem, flag);
}